// Round 1
// 440.780 us; speedup vs baseline: 1.5494x; 1.5494x over previous
//
#include <hip/hip_runtime.h>
#include <stdint.h>

#define D 128
#define Ssz 10
#define WP 136   // LDS row pad (u16) for rnn weight/h staging

typedef uint16_t u16;
typedef uint32_t u32;
typedef __attribute__((ext_vector_type(8))) short short8;
typedef __attribute__((ext_vector_type(4))) float f32x4;

#define AS1U32(p) ((const __attribute__((address_space(1))) u32*)(p))
#define AS3U32(p) ((__attribute__((address_space(3))) u32*)(p))

__device__ __forceinline__ u16 f2bf(float f){
  u32 x = __float_as_uint(f);
  return (u16)((x + 0x7fffu + ((x >> 16) & 1u)) >> 16);   // RNE
}
__device__ __forceinline__ float bf2f(u16 u){ return __uint_as_float(((u32)u) << 16); }

// WT[n*K + k] = bf16(W[k*D + n])   (W is f32 [K][128])
__global__ __launch_bounds__(256) void transpose_k(const float* __restrict__ W,
                                                   u16* __restrict__ WT, int K){
  int i = blockIdx.x * 256 + threadIdx.x;
  if (i >= K * D) return;
  int n = i / K, k = i - n * K;
  WT[i] = f2bf(W[k * D + n]);
}

// f32 -> bf16 elementwise (2 elems/thread)
__global__ __launch_bounds__(256) void cvt_bf16(const float* __restrict__ in,
                                                u16* __restrict__ out, int n2){
  int i = blockIdx.x * 256 + threadIdx.x;
  if (i >= n2) return;
  float v0 = in[2 * i], v1 = in[2 * i + 1];
  ((u32*)out)[i] = (u32)f2bf(v0) | ((u32)f2bf(v1) << 16);
}

// DENSE projection of a whole feature table:
// out[m][n] = feats[m][:K] . WT[n][:K] + bias[n],  m in [0, M)
// grid.x = ceil(M/64), block 256 (4 waves x 16 rows each), N = 128.
// B k-chunks (128x128 bf16 = 32 KB) staged via global_load_lds (XOR-16 chunk
// swizzle); A double-buffered in registers with COMPILE-TIME phase.
__global__ __launch_bounds__(256) void proj_gemm(
    const float* __restrict__ feats, int K, int M,
    const u16* __restrict__ WT,       // bf16 [128][K]
    const float* __restrict__ bias,   // f32 [128]
    u16* __restrict__ outb,           // bf16 [M][128] or null
    float* __restrict__ outf)         // f32  [M][128] or null
{
  __shared__ u16 Bt[128 * 128];       // [n][p] p = swizzled 8-elem chunk pos

  int lane = threadIdx.x & 63;
  int wave = threadIdx.x >> 6;
  int quad = lane >> 4, l16 = lane & 15;
  int m0 = blockIdx.x * 64 + wave * 16;

  int row = min(m0 + l16, M - 1);
  const float* aptr = feats + (long)row * K + quad * 8;

  int st_nrow = wave * 32 + (lane >> 4);          // + j*4 per staging instr
  int st_p    = lane & 15;

  f32x4 acc[8];
#pragma unroll
  for (int nt = 0; nt < 8; ++nt){
    float bv = bias[nt * 16 + l16];
    f32x4 t = {bv, bv, bv, bv};
    acc[nt] = t;
  }

  f32x4 afA[4][2], afB[4][2];
#pragma unroll
  for (int ks = 0; ks < 4; ++ks){
    afA[ks][0] = *(const f32x4*)(aptr + ks * 32);
    afA[ks][1] = *(const f32x4*)(aptr + ks * 32 + 4);
  }

  auto chunk_step = [&](f32x4 (&acur)[4][2], f32x4 (&anxt)[4][2], int kc) {
    // stage B chunk kc -> LDS (8 x 16B-per-lane instructions per wave)
#pragma unroll
    for (int j = 0; j < 8; ++j){
      int n = st_nrow + j * 4;
      int c = st_p ^ (n & 15);
      const u16* g = WT + (long)n * K + kc + c * 8;
      __builtin_amdgcn_global_load_lds(AS1U32(g),
                                       AS3U32(&Bt[(wave * 8 + j) * 512]),
                                       16, 0, 0);
    }
    // prefetch next A chunk into the alternate (named) buffer
    if (kc + 128 < K){
#pragma unroll
      for (int ks = 0; ks < 4; ++ks){
        anxt[ks][0] = *(const f32x4*)(aptr + kc + 128 + ks * 32);
        anxt[ks][1] = *(const f32x4*)(aptr + kc + 128 + ks * 32 + 4);
      }
    }
    __syncthreads();   // drains vmcnt -> LDS tile + current A ready

#pragma unroll
    for (int ks = 0; ks < 4; ++ks){
      short8 a;
#pragma unroll
      for (int q = 0; q < 4; ++q){
        a[q]     = (short)f2bf(acur[ks][0][q]);
        a[4 + q] = (short)f2bf(acur[ks][1][q]);
      }
#pragma unroll
      for (int nt = 0; nt < 8; ++nt){
        int n = nt * 16 + l16;
        int p = (ks * 4 + quad) ^ l16;
        short8 b = *(const short8*)(&Bt[n * 128 + p * 8]);
        acc[nt] = __builtin_amdgcn_mfma_f32_16x16x32_bf16(a, b, acc[nt], 0, 0, 0);
      }
    }
    __syncthreads();   // LDS reads done before next stage overwrites
  };

  for (int kc = 0; kc < K; kc += 256){
    chunk_step(afA, afB, kc);
    chunk_step(afB, afA, kc + 128);
  }

#pragma unroll
  for (int nt = 0; nt < 8; ++nt){
    int col = nt * 16 + l16;
#pragma unroll
    for (int r = 0; r < 4; ++r){
      int mr = m0 + quad * 4 + r;
      if (mr < M){
        long o = (long)mr * D + col;
        if (outb) outb[o] = f2bf(acc[nt][r]);
        if (outf) outf[o] = acc[nt][r];
      }
    }
  }
}

// out f32[r][:] = tab f32[clamp(idx[r])][:]; 64 lanes/row, float2/lane
__global__ __launch_bounds__(256) void gather_f32(
    const float* __restrict__ tab, const int* __restrict__ idx,
    float* __restrict__ out, int nrows, int ntab)
{
  int gt = blockIdx.x * 256 + threadIdx.x;
  int r = gt >> 6, c = gt & 63;
  if (r >= nrows) return;
  int row = min(max(idx[r], 0), ntab - 1);
  ((float2*)out)[(long)r * 64 + c] = ((const float2*)tab)[(long)row * 64 + c];
}

// Fused 3-type RNN: grid = (CB/16, 3); block 256 = 4 waves; wave w owns
// cols [32w, 32w+32). x rows gathered directly from the pre-projected
// bf16 table (L2-resident). Single reused LDS weight buffer (Wx then Wh)
// keeps LDS at 39 KB -> 3 blocks/CU co-resident (was 1).
__global__ __launch_bounds__(256, 3) void rnn3_kernel(
    const u16* __restrict__ tab0, const u16* __restrict__ tab1,
    const u16* __restrict__ tab2,
    const int* __restrict__ idx0, const int* __restrict__ idx1,
    const int* __restrict__ idx2,
    const float* __restrict__ Wx,    // f32 [3][128][128] (this layer)
    const float* __restrict__ Wh,
    const float* __restrict__ bvec,  // f32 [3][128]
    u16* __restrict__ agg, int CB)   // bf16 [3][CB][128]
{
  __shared__ u16 WT[D * WP];         // staged Wx, then overwritten with Wh
  __shared__ u16 hbuf[16 * WP];

  int t = blockIdx.y;
  const u16* tab = (t == 0) ? tab0 : (t == 1) ? tab1 : tab2;
  const int* idx = (t == 0) ? idx0 : (t == 1) ? idx1 : idx2;
  const float* Wxp = Wx + (size_t)t * D * D;
  const float* Whp = Wh + (size_t)t * D * D;

  int tid = threadIdx.x;
  int lane = tid & 63, wave = tid >> 6;
  int quad = lane >> 4, l16 = lane & 15;
  int n0 = wave * 32;

  for (int i = tid; i < D * D; i += 256){
    int n = i >> 7, k = i & 127;
    WT[n * WP + k] = f2bf(Wxp[k * D + n]);
  }
  for (int i = tid; i < 16 * WP; i += 256) hbuf[i] = 0;  // h0 = zeros
  __syncthreads();

  short8 wxf[2][4], whf[2][4];
#pragma unroll
  for (int nt = 0; nt < 2; ++nt){
    int n = n0 + nt * 16 + l16;
#pragma unroll
    for (int ks = 0; ks < 4; ++ks)
      wxf[nt][ks] = *(const short8*)(&WT[n * WP + ks * 32 + quad * 8]);
  }
  __syncthreads();   // all wxf reads done before overwrite
  for (int i = tid; i < D * D; i += 256){
    int n = i >> 7, k = i & 127;
    WT[n * WP + k] = f2bf(Whp[k * D + n]);
  }
  __syncthreads();
#pragma unroll
  for (int nt = 0; nt < 2; ++nt){
    int n = n0 + nt * 16 + l16;
#pragma unroll
    for (int ks = 0; ks < 4; ++ks)
      whf[nt][ks] = *(const short8*)(&WT[n * WP + ks * 32 + quad * 8]);
  }

  float bias0 = bvec[t * D + n0 + l16];
  float bias1 = bvec[t * D + n0 + 16 + l16];

  int b0 = blockIdx.x * 16;
  int nid[Ssz];
#pragma unroll
  for (int s = 0; s < Ssz; ++s) nid[s] = idx[(b0 + l16) * Ssz + s];

  short8 xc[4], xn[4];
  {
    const u16* xb = tab + (long)nid[0] * D + quad * 8;
#pragma unroll
    for (int ks = 0; ks < 4; ++ks) xc[ks] = *(const short8*)(xb + ks * 32);
  }

  for (int s = 0; s < Ssz; ++s){
    short8 hf[4];
#pragma unroll
    for (int ks = 0; ks < 4; ++ks)
      hf[ks] = *(const short8*)(&hbuf[l16 * WP + ks * 32 + quad * 8]);
    if (s + 1 < Ssz){
      const u16* xb = tab + (long)nid[s + 1] * D + quad * 8;
#pragma unroll
      for (int ks = 0; ks < 4; ++ks) xn[ks] = *(const short8*)(xb + ks * 32);
    }
    f32x4 acc0 = {bias0, bias0, bias0, bias0};
    f32x4 acc1 = {bias1, bias1, bias1, bias1};
#pragma unroll
    for (int ks = 0; ks < 4; ++ks){
      acc0 = __builtin_amdgcn_mfma_f32_16x16x32_bf16(xc[ks], wxf[0][ks], acc0, 0, 0, 0);
      acc0 = __builtin_amdgcn_mfma_f32_16x16x32_bf16(hf[ks], whf[0][ks], acc0, 0, 0, 0);
      acc1 = __builtin_amdgcn_mfma_f32_16x16x32_bf16(xc[ks], wxf[1][ks], acc1, 0, 0, 0);
      acc1 = __builtin_amdgcn_mfma_f32_16x16x32_bf16(hf[ks], whf[1][ks], acc1, 0, 0, 0);
    }
    __syncthreads();   // all waves done READING old h
#pragma unroll
    for (int r = 0; r < 4; ++r){
      float v0 = tanhf(acc0[r]);
      float v1 = tanhf(acc1[r]);
      hbuf[(quad * 4 + r) * WP + n0 + l16]      = f2bf(v0);
      hbuf[(quad * 4 + r) * WP + n0 + 16 + l16] = f2bf(v1);
      if (s == Ssz - 1){
        long row = (long)t * CB + b0 + quad * 4 + r;
        agg[row * D + n0 + l16]      = f2bf(v0);
        agg[row * D + n0 + 16 + l16] = f2bf(v1);
      }
    }
    __syncthreads();   // new h visible
#pragma unroll
    for (int ks = 0; ks < 4; ++ks) xc[ks] = xn[ks];
  }
}

// scores_c = leaky( h.aw[:128] + cand_c.aw[128:] ), softmax over 4, combine.
// one 64-lane wave per (local) row; lane owns elements {2*lane, 2*lane+1}
__global__ __launch_bounds__(256) void att_kernel(
    const float* __restrict__ h,   // f32 [CB][128]
    const u16* __restrict__ agg,   // bf16 [3][CB][128]
    const float* __restrict__ aw,  // f32 [256]
    float* __restrict__ out,       // f32 [CB][128]
    int CB)
{
  int gt = blockIdx.x * 256 + threadIdx.x;
  int lane = gt & 63;
  int b = gt >> 6;
  int e = 2 * lane;

  float c[4][2];
  c[0][0] = h[(long)b * D + e];
  c[0][1] = h[(long)b * D + e + 1];
#pragma unroll
  for (int t = 0; t < 3; ++t){
    c[t + 1][0] = bf2f(agg[((long)t * CB + b) * D + e]);
    c[t + 1][1] = bf2f(agg[((long)t * CB + b) * D + e + 1]);
  }
  float as0 = aw[e],     as1 = aw[e + 1];
  float ac0 = aw[D + e], ac1 = aw[D + e + 1];

  float selfp = c[0][0] * as0 + c[0][1] * as1;
  float sc[4];
#pragma unroll
  for (int cc = 0; cc < 4; ++cc) sc[cc] = selfp + c[cc][0] * ac0 + c[cc][1] * ac1;
#pragma unroll
  for (int off = 32; off >= 1; off >>= 1){
#pragma unroll
    for (int cc = 0; cc < 4; ++cc) sc[cc] += __shfl_xor(sc[cc], off, 64);
  }
#pragma unroll
  for (int cc = 0; cc < 4; ++cc) sc[cc] = sc[cc] > 0.f ? sc[cc] : 0.01f * sc[cc];

  float mx = fmaxf(fmaxf(sc[0], sc[1]), fmaxf(sc[2], sc[3]));
  float ex[4], ssum = 0.f;
#pragma unroll
  for (int cc = 0; cc < 4; ++cc){ ex[cc] = expf(sc[cc] - mx); ssum += ex[cc]; }
  float o0 = 0.f, o1 = 0.f;
#pragma unroll
  for (int cc = 0; cc < 4; ++cc){
    float a = ex[cc] / ssum;
    o0 += a * c[cc][0];
    o1 += a * c[cc][1];
  }
  out[(long)b * D + e]     = o0;
  out[(long)b * D + e + 1] = o1;
}

extern "C" void kernel_launch(void* const* d_in, const int* in_sizes, int n_in,
                              void* d_out, int out_size, void* d_ws, size_t ws_size,
                              hipStream_t stream)
{
  const float* drug_feats = (const float*)d_in[0];   // [4000][1024]
  const float* gene_feats = (const float*)d_in[1];   // [20000][2048]
  const float* cell_tab   = (const float*)d_in[2];   // [2000][128]
  const float* W_drug     = (const float*)d_in[3];   // [1024][128]
  const float* b_drug     = (const float*)d_in[4];   // [128]
  const float* W_gene     = (const float*)d_in[5];   // [2048][128]
  const float* b_gene     = (const float*)d_in[6];   // [128]
  const float* rnn_Wx     = (const float*)d_in[7];   // [2][3][128][128]
  const float* rnn_Wh     = (const float*)d_in[8];
  const float* rnn_b      = (const float*)d_in[9];   // [2][3][128]
  const float* att_w      = (const float*)d_in[10];  // [2][256]
  const int* center_ids   = (const int*)d_in[11];    // [4096]
  const int* cell_neigh   = (const int*)d_in[12];    // [2][4096][10]
  const int* drug_neigh   = (const int*)d_in[13];
  const int* gene_neigh   = (const int*)d_in[14];

  // ws (u16 elems):
  //  WdT [128*1024] | WgT [128*2048] | cellT [2000*128] | drugPb [4000*128]
  //  | genePb [20000*128] | drugPf f32 [4000*128] | agg [3*CB*128]
  // fixed bytes = 2*(131072+262144+256000+512000+2560000) + 4*512000 = 9,490,432
  u16* ws     = (u16*)d_ws;
  u16* WdT    = ws;
  u16* WgT    = WdT + 131072;
  u16* cellT  = WgT + 262144;
  u16* drugPb = cellT + 256000;
  u16* genePb = drugPb + 512000;
  float* drugPf = (float*)(genePb + 2560000);
  u16* agg    = (u16*)(drugPf + 512000);

  int CB = 4096;
  while (CB > 64){
    size_t need = 9490432u + (size_t)768 * CB;   // + agg bytes
    if (need <= ws_size) break;
    CB >>= 1;
  }
  float* h = (float*)d_out;               // f32 [4096][128] — h lives in d_out

  transpose_k<<<(1024 * D + 255) / 256, 256, 0, stream>>>(W_drug, WdT, 1024);
  transpose_k<<<(2048 * D + 255) / 256, 256, 0, stream>>>(W_gene, WgT, 2048);
  cvt_bf16<<<(2000 * 64 + 255) / 256, 256, 0, stream>>>(cell_tab, cellT, 2000 * 64);

  // Project FULL tables once (gather commutes with row-wise linear map).
  proj_gemm<<<(4000 + 63) / 64, 256, 0, stream>>>(drug_feats, 1024, 4000,
                                                  WdT, b_drug, drugPb, drugPf);
  proj_gemm<<<(20000 + 63) / 64, 256, 0, stream>>>(gene_feats, 2048, 20000,
                                                   WgT, b_gene, genePb,
                                                   (float*)nullptr);

  for (int b0 = 0; b0 < 4096; b0 += CB){
    // h0 = (drug_feats @ W_drug + b)[center_ids]  — f32 gather into d_out
    gather_f32<<<CB / 4, 256, 0, stream>>>(drugPf, center_ids + b0,
                                           h + (size_t)b0 * D, CB, 4000);
    for (int l = 0; l < 2; ++l){
      const int* cn = cell_neigh + ((size_t)l * 4096 + b0) * Ssz;
      const int* dn = drug_neigh + ((size_t)l * 4096 + b0) * Ssz;
      const int* gn = gene_neigh + ((size_t)l * 4096 + b0) * Ssz;

      rnn3_kernel<<<dim3(CB / 16, 3), 256, 0, stream>>>(
          cellT, drugPb, genePb, cn, dn, gn,
          rnn_Wx + (size_t)l * 3 * D * D,
          rnn_Wh + (size_t)l * 3 * D * D,
          rnn_b  + (size_t)l * 3 * D,
          agg, CB);

      att_kernel<<<CB / 4, 256, 0, stream>>>(h + (size_t)b0 * D, agg,
                                             att_w + (size_t)l * 2 * D,
                                             h + (size_t)b0 * D, CB);
    }
  }
}

// Round 4
// 366.683 us; speedup vs baseline: 1.8625x; 1.2021x over previous
//
#include <hip/hip_runtime.h>
#include <stdint.h>

#define D 128
#define Ssz 10
#define HP 136   // LDS row pad (u16) for rnn h staging — MUST be mult of 8
                 // (short8 LDS reads need 16B alignment; 130 faulted)

typedef uint16_t u16;
typedef uint32_t u32;
typedef __attribute__((ext_vector_type(8))) short short8;
typedef __attribute__((ext_vector_type(4))) float f32x4;

#define AS1U32(p) ((const __attribute__((address_space(1))) u32*)(p))
#define AS3U32(p) ((__attribute__((address_space(3))) u32*)(p))

__device__ __forceinline__ u16 f2bf(float f){
  u32 x = __float_as_uint(f);
  return (u16)((x + 0x7fffu + ((x >> 16) & 1u)) >> 16);   // RNE
}
__device__ __forceinline__ float bf2f(u16 u){ return __uint_as_float(((u32)u) << 16); }

// branch-free fast tanh: 1 - 2/(e^{2x}+1); exact at +-inf, abs err ~1e-7
__device__ __forceinline__ float ftanh(float x){
  float e = __expf(2.0f * x);
  return 1.0f - 2.0f / (e + 1.0f);
}

// WT[n*K + k] = bf16(W[k*D + n])   (W is f32 [K][128])
__global__ __launch_bounds__(256) void transpose_k(const float* __restrict__ W,
                                                   u16* __restrict__ WT, int K){
  int i = blockIdx.x * 256 + threadIdx.x;
  if (i >= K * D) return;
  int n = i / K, k = i - n * K;
  WT[i] = f2bf(W[k * D + n]);
}

// batch transpose of 6 contiguous [128][128] f32 mats -> bf16 [6][128][128] n-major
__global__ __launch_bounds__(256) void transpose_b6(const float* __restrict__ W,
                                                    u16* __restrict__ WT){
  int i = blockIdx.x * 256 + threadIdx.x;     // grid = 6*16384/256 = 384
  int j = i & 16383, n = j >> 7, k = j & 127;
  WT[i] = f2bf(W[(i & ~16383) + k * D + n]);
}

// f32 -> bf16 elementwise (2 elems/thread)
__global__ __launch_bounds__(256) void cvt_bf16(const float* __restrict__ in,
                                                u16* __restrict__ out, int n2){
  int i = blockIdx.x * 256 + threadIdx.x;
  if (i >= n2) return;
  float v0 = in[2 * i], v1 = in[2 * i + 1];
  ((u32*)out)[i] = (u32)f2bf(v0) | ((u32)f2bf(v1) << 16);
}

// DENSE projection of a whole feature table:
// out[m][n] = feats[m][:K] . WT[n][:K] + bias[n],  m in [0, M)
__global__ __launch_bounds__(256) void proj_gemm(
    const float* __restrict__ feats, int K, int M,
    const u16* __restrict__ WT,       // bf16 [128][K]
    const float* __restrict__ bias,   // f32 [128]
    u16* __restrict__ outb,           // bf16 [M][128] or null
    float* __restrict__ outf)         // f32  [M][128] or null
{
  __shared__ u16 Bt[128 * 128];       // [n][p] p = swizzled 8-elem chunk pos

  int lane = threadIdx.x & 63;
  int wave = threadIdx.x >> 6;
  int quad = lane >> 4, l16 = lane & 15;
  int m0 = blockIdx.x * 64 + wave * 16;

  int row = min(m0 + l16, M - 1);
  const float* aptr = feats + (long)row * K + quad * 8;

  int st_nrow = wave * 32 + (lane >> 4);
  int st_p    = lane & 15;

  f32x4 acc[8];
#pragma unroll
  for (int nt = 0; nt < 8; ++nt){
    float bv = bias[nt * 16 + l16];
    f32x4 t = {bv, bv, bv, bv};
    acc[nt] = t;
  }

  f32x4 afA[4][2], afB[4][2];
#pragma unroll
  for (int ks = 0; ks < 4; ++ks){
    afA[ks][0] = *(const f32x4*)(aptr + ks * 32);
    afA[ks][1] = *(const f32x4*)(aptr + ks * 32 + 4);
  }

  auto chunk_step = [&](f32x4 (&acur)[4][2], f32x4 (&anxt)[4][2], int kc) {
#pragma unroll
    for (int j = 0; j < 8; ++j){
      int n = st_nrow + j * 4;
      int c = st_p ^ (n & 15);
      const u16* g = WT + (long)n * K + kc + c * 8;
      __builtin_amdgcn_global_load_lds(AS1U32(g),
                                       AS3U32(&Bt[(wave * 8 + j) * 512]),
                                       16, 0, 0);
    }
    if (kc + 128 < K){
#pragma unroll
      for (int ks = 0; ks < 4; ++ks){
        anxt[ks][0] = *(const f32x4*)(aptr + kc + 128 + ks * 32);
        anxt[ks][1] = *(const f32x4*)(aptr + kc + 128 + ks * 32 + 4);
      }
    }
    __syncthreads();

#pragma unroll
    for (int ks = 0; ks < 4; ++ks){
      short8 a;
#pragma unroll
      for (int q = 0; q < 4; ++q){
        a[q]     = (short)f2bf(acur[ks][0][q]);
        a[4 + q] = (short)f2bf(acur[ks][1][q]);
      }
#pragma unroll
      for (int nt = 0; nt < 8; ++nt){
        int n = nt * 16 + l16;
        int p = (ks * 4 + quad) ^ l16;
        short8 b = *(const short8*)(&Bt[n * 128 + p * 8]);
        acc[nt] = __builtin_amdgcn_mfma_f32_16x16x32_bf16(a, b, acc[nt], 0, 0, 0);
      }
    }
    __syncthreads();
  };

  for (int kc = 0; kc < K; kc += 256){
    chunk_step(afA, afB, kc);
    chunk_step(afB, afA, kc + 128);
  }

#pragma unroll
  for (int nt = 0; nt < 8; ++nt){
    int col = nt * 16 + l16;
#pragma unroll
    for (int r = 0; r < 4; ++r){
      int mr = m0 + quad * 4 + r;
      if (mr < M){
        long o = (long)mr * D + col;
        if (outb) outb[o] = f2bf(acc[nt][r]);
        if (outf) outf[o] = acc[nt][r];
      }
    }
  }
}

// xwb[l][rbase+m][n] = tabP[m][:128] . WxT6[l*3+t][n][:128] + b[l*3+t][n]
// K=128, bf16 A from projected tables, B direct from L2-hot transposed weights.
// grid = (408, 2): blocks [0,32) cell, [32,95) drug, [95,408) gene.
__global__ __launch_bounds__(256) void xw_gemm(
    const u16* __restrict__ cellT, const u16* __restrict__ drugPb,
    const u16* __restrict__ genePb,
    const u16* __restrict__ WxT6,   // bf16 [6][128][128]
    const float* __restrict__ bvec, // f32 [6][128]
    float* __restrict__ xwb)        // f32 [2][26000][128]
{
  int bx = blockIdx.x, l = blockIdx.y;
  int t, m0, M, rbase;
  const u16* tab;
  if (bx < 32)      { t = 0; m0 = bx * 64;        M = 2000;  rbase = 0;    tab = cellT; }
  else if (bx < 95) { t = 1; m0 = (bx - 32) * 64; M = 4000;  rbase = 2000; tab = drugPb; }
  else              { t = 2; m0 = (bx - 95) * 64; M = 20000; rbase = 6000; tab = genePb; }
  int mat = l * 3 + t;
  const u16* WT = WxT6 + (size_t)mat * 16384;

  int lane = threadIdx.x & 63, wave = threadIdx.x >> 6;
  int quad = lane >> 4, l16 = lane & 15;
  int mt = m0 + wave * 16;
  int mr = min(mt + l16, M - 1);

  short8 a[4];
#pragma unroll
  for (int ks = 0; ks < 4; ++ks)
    a[ks] = *(const short8*)(tab + (long)mr * D + ks * 32 + quad * 8);

  f32x4 acc[8];
#pragma unroll
  for (int nt = 0; nt < 8; ++nt){
    float bv = bvec[mat * D + nt * 16 + l16];
    f32x4 tv = {bv, bv, bv, bv};
    acc[nt] = tv;
  }
#pragma unroll
  for (int nt = 0; nt < 8; ++nt){
#pragma unroll
    for (int ks = 0; ks < 4; ++ks){
      short8 b = *(const short8*)(WT + (nt * 16 + l16) * D + ks * 32 + quad * 8);
      acc[nt] = __builtin_amdgcn_mfma_f32_16x16x32_bf16(a[ks], b, acc[nt], 0, 0, 0);
    }
  }
#pragma unroll
  for (int nt = 0; nt < 8; ++nt){
    int col = nt * 16 + l16;
#pragma unroll
    for (int r = 0; r < 4; ++r){
      int mrow = mt + quad * 4 + r;
      if (mrow < M)
        xwb[((long)l * 26000 + rbase + mrow) * D + col] = acc[nt][r];
    }
  }
}

// out f32[r][:] = tab f32[clamp(idx[r])][:]; 64 lanes/row, float2/lane
__global__ __launch_bounds__(256) void gather_f32(
    const float* __restrict__ tab, const int* __restrict__ idx,
    float* __restrict__ out, int nrows, int ntab)
{
  int gt = blockIdx.x * 256 + threadIdx.x;
  int r = gt >> 6, c = gt & 63;
  if (r >= nrows) return;
  int row = min(max(idx[r], 0), ntab - 1);
  ((float2*)out)[(long)r * 64 + c] = ((const float2*)tab)[(long)row * 64 + c];
}

// Fused 6-way RNN (3 types x 2 layers): grid = (CB/16, 3, 2), block 256 = 4 waves.
// h = tanh(xw_gathered + h @ Wh); serial part is 8 MFMAs + 8 fast-tanh per step.
// Wh frags read once from pre-transposed global (L2); LDS = 4.4 KB (h only).
// s-loop fully unrolled via 10 static calls (no runtime-indexed arrays).
__global__ __launch_bounds__(256, 3) void rnn6_kernel(
    const float* __restrict__ xwb,   // f32 [2][26000][128]
    const u16* __restrict__ WhT6,    // bf16 [6][128][128]
    const int* __restrict__ cn, const int* __restrict__ dn,
    const int* __restrict__ gn,      // [2][4096][10]
    int b0,
    u16* __restrict__ agg, int CB)   // bf16 [2][3][CB][128]
{
  __shared__ u16 hbuf[16 * HP];

  int t = blockIdx.y, l = blockIdx.z;
  const int* idx = (t == 0) ? cn : (t == 1) ? dn : gn;
  int rbase = (t == 0) ? 0 : (t == 1) ? 2000 : 6000;
  int nmax  = (t == 0) ? 2000 : (t == 1) ? 4000 : 20000;
  const float* xw = xwb + ((size_t)l * 26000 + rbase) * D;
  const u16* WT = WhT6 + (size_t)(l * 3 + t) * 16384;

  int tid = threadIdx.x, lane = tid & 63, wave = tid >> 6;
  int quad = lane >> 4, l16 = lane & 15;
  int n0 = wave * 32;

  short8 whf[2][4];
#pragma unroll
  for (int nt = 0; nt < 2; ++nt){
    int n = n0 + nt * 16 + l16;
#pragma unroll
    for (int ks = 0; ks < 4; ++ks)
      whf[nt][ks] = *(const short8*)(WT + n * D + ks * 32 + quad * 8);
  }

  for (int i = tid; i < 16 * HP; i += 256) hbuf[i] = 0;   // h0 = zeros

  int brow = blockIdx.x * 16;
  const int* ip = idx + ((size_t)l * 4096 + b0 + brow + quad * 4) * Ssz;
  long arow = ((long)(l * 3 + t) * CB + brow) * D;

  int nidA[4], nidB[4];
  float xwA[8], xwB[8];
#pragma unroll
  for (int r = 0; r < 4; ++r) nidA[r] = min(max(ip[r * Ssz], 0), nmax - 1);
#pragma unroll
  for (int r = 0; r < 4; ++r){
    const float* p = xw + (long)nidA[r] * D + n0 + l16;
    xwA[r] = p[0]; xwA[4 + r] = p[16];
  }
#pragma unroll
  for (int r = 0; r < 4; ++r) nidB[r] = min(max(ip[r * Ssz + 1], 0), nmax - 1);
  __syncthreads();   // hbuf zeros visible

  auto step = [&](int s, float (&xwc)[8], int (&nidn)[4],
                  float (&xwn)[8], int (&nidf)[4]){
    if (s + 1 < Ssz){
#pragma unroll
      for (int r = 0; r < 4; ++r){
        const float* p = xw + (long)nidn[r] * D + n0 + l16;
        xwn[r] = p[0]; xwn[4 + r] = p[16];
      }
    }
    if (s + 2 < Ssz){
#pragma unroll
      for (int r = 0; r < 4; ++r)
        nidf[r] = min(max(ip[r * Ssz + s + 2], 0), nmax - 1);
    }
    short8 hf[4];
#pragma unroll
    for (int ks = 0; ks < 4; ++ks)
      hf[ks] = *(const short8*)(&hbuf[l16 * HP + ks * 32 + quad * 8]);
    f32x4 acc0 = {xwc[0], xwc[1], xwc[2], xwc[3]};
    f32x4 acc1 = {xwc[4], xwc[5], xwc[6], xwc[7]};
#pragma unroll
    for (int ks = 0; ks < 4; ++ks){
      acc0 = __builtin_amdgcn_mfma_f32_16x16x32_bf16(hf[ks], whf[0][ks], acc0, 0, 0, 0);
      acc1 = __builtin_amdgcn_mfma_f32_16x16x32_bf16(hf[ks], whf[1][ks], acc1, 0, 0, 0);
    }
    __syncthreads();   // all waves done READING old h
#pragma unroll
    for (int r = 0; r < 4; ++r){
      float v0 = ftanh(acc0[r]);
      float v1 = ftanh(acc1[r]);
      hbuf[(quad * 4 + r) * HP + n0 + l16]      = f2bf(v0);
      hbuf[(quad * 4 + r) * HP + n0 + 16 + l16] = f2bf(v1);
      if (s == Ssz - 1){
        long o = arow + (long)(quad * 4 + r) * D;
        agg[o + n0 + l16]      = f2bf(v0);
        agg[o + n0 + 16 + l16] = f2bf(v1);
      }
    }
    __syncthreads();   // new h visible
  };

  step(0, xwA, nidB, xwB, nidA);
  step(1, xwB, nidA, xwA, nidB);
  step(2, xwA, nidB, xwB, nidA);
  step(3, xwB, nidA, xwA, nidB);
  step(4, xwA, nidB, xwB, nidA);
  step(5, xwB, nidA, xwA, nidB);
  step(6, xwA, nidB, xwB, nidA);
  step(7, xwB, nidA, xwA, nidB);
  step(8, xwA, nidB, xwB, nidA);
  step(9, xwB, nidA, xwA, nidB);
}

// scores_c = leaky( h.aw[:128] + cand_c.aw[128:] ), softmax over 4, combine.
__global__ __launch_bounds__(256) void att_kernel(
    const float* __restrict__ h,   // f32 [CB][128]
    const u16* __restrict__ agg,   // bf16 [3][CB][128]
    const float* __restrict__ aw,  // f32 [256]
    float* __restrict__ out,       // f32 [CB][128]
    int CB)
{
  int gt = blockIdx.x * 256 + threadIdx.x;
  int lane = gt & 63;
  int b = gt >> 6;
  int e = 2 * lane;

  float c[4][2];
  c[0][0] = h[(long)b * D + e];
  c[0][1] = h[(long)b * D + e + 1];
#pragma unroll
  for (int t = 0; t < 3; ++t){
    c[t + 1][0] = bf2f(agg[((long)t * CB + b) * D + e]);
    c[t + 1][1] = bf2f(agg[((long)t * CB + b) * D + e + 1]);
  }
  float as0 = aw[e],     as1 = aw[e + 1];
  float ac0 = aw[D + e], ac1 = aw[D + e + 1];

  float selfp = c[0][0] * as0 + c[0][1] * as1;
  float sc[4];
#pragma unroll
  for (int cc = 0; cc < 4; ++cc) sc[cc] = selfp + c[cc][0] * ac0 + c[cc][1] * ac1;
#pragma unroll
  for (int off = 32; off >= 1; off >>= 1){
#pragma unroll
    for (int cc = 0; cc < 4; ++cc) sc[cc] += __shfl_xor(sc[cc], off, 64);
  }
#pragma unroll
  for (int cc = 0; cc < 4; ++cc) sc[cc] = sc[cc] > 0.f ? sc[cc] : 0.01f * sc[cc];

  float mx = fmaxf(fmaxf(sc[0], sc[1]), fmaxf(sc[2], sc[3]));
  float ex[4], ssum = 0.f;
#pragma unroll
  for (int cc = 0; cc < 4; ++cc){ ex[cc] = expf(sc[cc] - mx); ssum += ex[cc]; }
  float o0 = 0.f, o1 = 0.f;
#pragma unroll
  for (int cc = 0; cc < 4; ++cc){
    float a = ex[cc] / ssum;
    o0 += a * c[cc][0];
    o1 += a * c[cc][1];
  }
  out[(long)b * D + e]     = o0;
  out[(long)b * D + e + 1] = o1;
}

extern "C" void kernel_launch(void* const* d_in, const int* in_sizes, int n_in,
                              void* d_out, int out_size, void* d_ws, size_t ws_size,
                              hipStream_t stream)
{
  const float* drug_feats = (const float*)d_in[0];   // [4000][1024]
  const float* gene_feats = (const float*)d_in[1];   // [20000][2048]
  const float* cell_tab   = (const float*)d_in[2];   // [2000][128]
  const float* W_drug     = (const float*)d_in[3];   // [1024][128]
  const float* b_drug     = (const float*)d_in[4];   // [128]
  const float* W_gene     = (const float*)d_in[5];   // [2048][128]
  const float* b_gene     = (const float*)d_in[6];   // [128]
  const float* rnn_Wx     = (const float*)d_in[7];   // [2][3][128][128]
  const float* rnn_Wh     = (const float*)d_in[8];
  const float* rnn_b      = (const float*)d_in[9];   // [2][3][128]
  const float* att_w      = (const float*)d_in[10];  // [2][256]
  const int* center_ids   = (const int*)d_in[11];    // [4096]
  const int* cell_neigh   = (const int*)d_in[12];    // [2][4096][10]
  const int* drug_neigh   = (const int*)d_in[13];
  const int* gene_neigh   = (const int*)d_in[14];

  // ws layout (u16 units):
  //  WdT 131072 | WgT 262144 | WxT6 98304 | WhT6 98304 | cellT 256000
  //  | drugPb 512000 | genePb 2560000 | drugPf f32 512000 | xwb f32 6656000
  //  | agg 6*CB*128
  u16* ws     = (u16*)d_ws;
  u16* WdT    = ws;
  u16* WgT    = WdT + 131072;
  u16* WxT6   = WgT + 262144;
  u16* WhT6   = WxT6 + 98304;
  u16* cellT  = WhT6 + 98304;
  u16* drugPb = cellT + 256000;
  u16* genePb = drugPb + 512000;
  float* drugPf = (float*)(genePb + 2560000);
  float* xwb    = drugPf + 512000;
  u16* agg      = (u16*)(xwb + 6656000);

  // fixed bytes = 7,835,648 + 2,048,000 + 26,624,000 = 36,507,648
  int CB = 4096;
  while (CB > 64){
    size_t need = 36507648u + (size_t)1536 * CB;
    if (need <= ws_size) break;
    CB >>= 1;
  }
  float* h = (float*)d_out;               // f32 [4096][128]

  transpose_k<<<512, 256, 0, stream>>>(W_drug, WdT, 1024);
  transpose_k<<<1024, 256, 0, stream>>>(W_gene, WgT, 2048);
  transpose_b6<<<384, 256, 0, stream>>>(rnn_Wx, WxT6);
  transpose_b6<<<384, 256, 0, stream>>>(rnn_Wh, WhT6);
  cvt_bf16<<<500, 256, 0, stream>>>(cell_tab, cellT, 2000 * 64);

  // Project FULL tables once (gather commutes with row-wise linear map).
  proj_gemm<<<63, 256, 0, stream>>>(drug_feats, 1024, 4000,
                                    WdT, b_drug, drugPb, drugPf);
  proj_gemm<<<313, 256, 0, stream>>>(gene_feats, 2048, 20000,
                                     WgT, b_gene, genePb, (float*)nullptr);

  // Hoist x@Wx out of the serial RNN: per-(layer,type) projected-table @ Wx + b.
  xw_gemm<<<dim3(408, 2), 256, 0, stream>>>(cellT, drugPb, genePb,
                                            WxT6, rnn_b, xwb);

  for (int b0 = 0; b0 < 4096; b0 += CB){
    gather_f32<<<CB / 4, 256, 0, stream>>>(drugPf, center_ids + b0,
                                           h + (size_t)b0 * D, CB, 4000);
    // all 6 (layer,type) RNN aggregations are h-independent -> one launch
    rnn6_kernel<<<dim3(CB / 16, 3, 2), 256, 0, stream>>>(
        xwb, WhT6, cell_neigh, drug_neigh, gene_neigh, b0, agg, CB);

    for (int l = 0; l < 2; ++l){
      att_kernel<<<CB / 4, 256, 0, stream>>>(h + (size_t)b0 * D,
                                             agg + (size_t)l * 3 * CB * D,
                                             att_w + (size_t)l * 2 * D,
                                             h + (size_t)b0 * D, CB);
    }
  }
}

// Round 5
// 360.932 us; speedup vs baseline: 1.8921x; 1.0159x over previous
//
#include <hip/hip_runtime.h>
#include <stdint.h>

#define D 128
#define Ssz 10
#define HP 136   // LDS row pad (u16) — 272 B row stride, 16B-aligned (mult of 8!)
#define NB 4096  // batch

typedef uint16_t u16;
typedef uint32_t u32;
typedef __attribute__((ext_vector_type(8))) short short8;
typedef __attribute__((ext_vector_type(4))) float f32x4;

#define AS1U32(p) ((const __attribute__((address_space(1))) u32*)(p))
#define AS3U32(p) ((__attribute__((address_space(3))) u32*)(p))

__device__ __forceinline__ u16 f2bf(float f){
  u32 x = __float_as_uint(f);
  return (u16)((x + 0x7fffu + ((x >> 16) & 1u)) >> 16);   // RNE
}
__device__ __forceinline__ float bf2f(u16 u){ return __uint_as_float(((u32)u) << 16); }

// branch-free fast tanh: 1 - 2/(e^{2x}+1); exact at +-inf, abs err ~1e-7
__device__ __forceinline__ float ftanh(float x){
  float e = __expf(2.0f * x);
  return 1.0f - 2.0f / (e + 1.0f);
}

// Fused preamble: all weight transposes + cell cvt in one launch.
// segments (all multiples of 256):
//  [0,131072)          WdT[n*1024+k]  = bf16(W_drug[k*128+n])
//  [131072,393216)     WgT[n*2048+k]  = bf16(W_gene[k*128+n])
//  [393216,491520)     WxT6[mat][n][k]= bf16(rnn_Wx[mat][k][n])
//  [491520,589824)     WhT6 likewise
//  [589824,717824)     cellT: 2 f32 -> packed 2xbf16 per thread
__global__ __launch_bounds__(256) void prep_kernel(
    const float* __restrict__ W_drug, const float* __restrict__ W_gene,
    const float* __restrict__ rnn_Wx, const float* __restrict__ rnn_Wh,
    const float* __restrict__ cell_tab,
    u16* __restrict__ WdT, u16* __restrict__ WgT,
    u16* __restrict__ WxT6, u16* __restrict__ WhT6,
    u16* __restrict__ cellT)
{
  int i = blockIdx.x * 256 + threadIdx.x;
  if (i < 131072){
    int n = i >> 10, k = i & 1023;
    WdT[i] = f2bf(W_drug[k * D + n]);
  } else if (i < 393216){
    int j = i - 131072;
    int n = j >> 11, k = j & 2047;
    WgT[j] = f2bf(W_gene[k * D + n]);
  } else if (i < 491520){
    int j = i - 393216;
    int n = (j >> 7) & 127, k = j & 127;
    WxT6[j] = f2bf(rnn_Wx[(j & ~16383) + k * D + n]);
  } else if (i < 589824){
    int j = i - 491520;
    int n = (j >> 7) & 127, k = j & 127;
    WhT6[j] = f2bf(rnn_Wh[(j & ~16383) + k * D + n]);
  } else {
    int j = i - 589824;                 // j < 128000
    float v0 = cell_tab[2 * j], v1 = cell_tab[2 * j + 1];
    ((u32*)cellT)[j] = (u32)f2bf(v0) | ((u32)f2bf(v1) << 16);
  }
}

// DENSE projection of a whole feature table + fused per-layer x@Wx epilogue:
//   P[m][n]     = feats[m][:K] . WT[n][:K] + bias[n]
//   xw{0,1}[m]  = bf16(P[m]) @ Wx{0,1} + rb{0,1}      (f32 out, for the RNN)
//   outf[m]     = P[m] (f32, optional — drug table for h0 gather)
__global__ __launch_bounds__(256) void proj_gemm(
    const float* __restrict__ feats, int K, int M,
    const u16* __restrict__ WT,       // bf16 [128][K]
    const float* __restrict__ bias,   // f32 [128]
    const u16* __restrict__ Wx0,      // bf16 [128][128] n-major (layer 0)
    const u16* __restrict__ Wx1,      // layer 1
    const float* __restrict__ rb0,    // rnn bias [128]
    const float* __restrict__ rb1,
    float* __restrict__ xw0,          // f32 [M][128] (xwb slice, layer 0)
    float* __restrict__ xw1,
    float* __restrict__ outf)         // f32 [M][128] or null
{
  __shared__ u16 Bt[128 * 128];       // [n][p] swizzled 8-elem chunks; reused as P-tile

  int lane = threadIdx.x & 63;
  int wave = threadIdx.x >> 6;
  int quad = lane >> 4, l16 = lane & 15;
  int m0 = blockIdx.x * 64 + wave * 16;

  int row = min(m0 + l16, M - 1);
  const float* aptr = feats + (long)row * K + quad * 8;

  int st_nrow = wave * 32 + (lane >> 4);
  int st_p    = lane & 15;

  f32x4 acc[8];
#pragma unroll
  for (int nt = 0; nt < 8; ++nt){
    float bv = bias[nt * 16 + l16];
    f32x4 t = {bv, bv, bv, bv};
    acc[nt] = t;
  }

  f32x4 afA[4][2], afB[4][2];
#pragma unroll
  for (int ks = 0; ks < 4; ++ks){
    afA[ks][0] = *(const f32x4*)(aptr + ks * 32);
    afA[ks][1] = *(const f32x4*)(aptr + ks * 32 + 4);
  }

  auto chunk_step = [&](f32x4 (&acur)[4][2], f32x4 (&anxt)[4][2], int kc) {
#pragma unroll
    for (int j = 0; j < 8; ++j){
      int n = st_nrow + j * 4;
      int c = st_p ^ (n & 15);
      const u16* g = WT + (long)n * K + kc + c * 8;
      __builtin_amdgcn_global_load_lds(AS1U32(g),
                                       AS3U32(&Bt[(wave * 8 + j) * 512]),
                                       16, 0, 0);
    }
    if (kc + 128 < K){
#pragma unroll
      for (int ks = 0; ks < 4; ++ks){
        anxt[ks][0] = *(const f32x4*)(aptr + kc + 128 + ks * 32);
        anxt[ks][1] = *(const f32x4*)(aptr + kc + 128 + ks * 32 + 4);
      }
    }
    __syncthreads();

#pragma unroll
    for (int ks = 0; ks < 4; ++ks){
      short8 a;
#pragma unroll
      for (int q = 0; q < 4; ++q){
        a[q]     = (short)f2bf(acur[ks][0][q]);
        a[4 + q] = (short)f2bf(acur[ks][1][q]);
      }
#pragma unroll
      for (int nt = 0; nt < 8; ++nt){
        int n = nt * 16 + l16;
        int p = (ks * 4 + quad) ^ l16;
        short8 b = *(const short8*)(&Bt[n * 128 + p * 8]);
        acc[nt] = __builtin_amdgcn_mfma_f32_16x16x32_bf16(a, b, acc[nt], 0, 0, 0);
      }
    }
    __syncthreads();
  };

  for (int kc = 0; kc < K; kc += 256){
    chunk_step(afA, afB, kc);
    chunk_step(afB, afA, kc + 128);
  }

  // ---- epilogue: optional f32 P output ----
  if (outf){
#pragma unroll
    for (int nt = 0; nt < 8; ++nt){
      int col = nt * 16 + l16;
#pragma unroll
      for (int r = 0; r < 4; ++r){
        int mr = m0 + quad * 4 + r;
        if (mr < M) outf[(long)mr * D + col] = acc[nt][r];
      }
    }
  }

  // ---- epilogue: xw = bf16(P) @ Wx + rb for both layers ----
  // stash wave's 16x128 P-tile (bf16) in padded LDS [16][136] (272B rows, aligned)
  u16* Pl = Bt + wave * 2176;
#pragma unroll
  for (int nt = 0; nt < 8; ++nt)
#pragma unroll
    for (int r = 0; r < 4; ++r)
      Pl[(quad * 4 + r) * HP + nt * 16 + l16] = f2bf(acc[nt][r]);
  __syncthreads();

  short8 paf[4];
#pragma unroll
  for (int ks = 0; ks < 4; ++ks)
    paf[ks] = *(const short8*)(&Pl[l16 * HP + ks * 32 + quad * 8]);

  auto xw_pass = [&](const u16* Wx, const float* rb, float* xw){
    f32x4 ac2[8];
#pragma unroll
    for (int nt = 0; nt < 8; ++nt){
      float bv = rb[nt * 16 + l16];
      f32x4 tv = {bv, bv, bv, bv};
      ac2[nt] = tv;
    }
#pragma unroll
    for (int nt = 0; nt < 8; ++nt){
#pragma unroll
      for (int ks = 0; ks < 4; ++ks){
        short8 b = *(const short8*)(Wx + (nt * 16 + l16) * D + ks * 32 + quad * 8);
        ac2[nt] = __builtin_amdgcn_mfma_f32_16x16x32_bf16(paf[ks], b, ac2[nt], 0, 0, 0);
      }
    }
#pragma unroll
    for (int nt = 0; nt < 8; ++nt){
      int col = nt * 16 + l16;
#pragma unroll
      for (int r = 0; r < 4; ++r){
        int mr = m0 + quad * 4 + r;
        if (mr < M) xw[(long)mr * D + col] = ac2[nt][r];
      }
    }
  };
  xw_pass(Wx0, rb0, xw0);
  xw_pass(Wx1, rb1, xw1);
}

// xw for the cell type (table already 128-wide bf16): grid (32, 2)
__global__ __launch_bounds__(256) void xw_cell(
    const u16* __restrict__ cellT,  // bf16 [2000][128]
    const u16* __restrict__ WxT6,   // bf16 [6][128][128]
    const float* __restrict__ bvec, // f32 [6][128] (rnn_b)
    float* __restrict__ xwb)        // f32 [2][26000][128]
{
  int l = blockIdx.y;
  int mat = l * 3;                  // type 0 = cell
  const u16* WT = WxT6 + (size_t)mat * 16384;

  int lane = threadIdx.x & 63, wave = threadIdx.x >> 6;
  int quad = lane >> 4, l16 = lane & 15;
  int mt = blockIdx.x * 64 + wave * 16;
  int mr = min(mt + l16, 1999);

  short8 a[4];
#pragma unroll
  for (int ks = 0; ks < 4; ++ks)
    a[ks] = *(const short8*)(cellT + (long)mr * D + ks * 32 + quad * 8);

  f32x4 acc[8];
#pragma unroll
  for (int nt = 0; nt < 8; ++nt){
    float bv = bvec[mat * D + nt * 16 + l16];
    f32x4 tv = {bv, bv, bv, bv};
    acc[nt] = tv;
  }
#pragma unroll
  for (int nt = 0; nt < 8; ++nt){
#pragma unroll
    for (int ks = 0; ks < 4; ++ks){
      short8 b = *(const short8*)(WT + (nt * 16 + l16) * D + ks * 32 + quad * 8);
      acc[nt] = __builtin_amdgcn_mfma_f32_16x16x32_bf16(a[ks], b, acc[nt], 0, 0, 0);
    }
  }
#pragma unroll
  for (int nt = 0; nt < 8; ++nt){
    int col = nt * 16 + l16;
#pragma unroll
    for (int r = 0; r < 4; ++r){
      int mrow = mt + quad * 4 + r;
      if (mrow < 2000)
        xwb[((long)l * 26000 + mrow) * D + col] = acc[nt][r];
    }
  }
}

// Fused 6-way RNN (3 types x 2 layers): grid = (256, 3, 2), block 256 = 4 waves.
// h = tanh(xw_gathered + h @ Wh). Proven round-4 structure (HP=136 aligned).
__global__ __launch_bounds__(256, 3) void rnn6_kernel(
    const float* __restrict__ xwb,   // f32 [2][26000][128]
    const u16* __restrict__ WhT6,    // bf16 [6][128][128]
    const int* __restrict__ cn, const int* __restrict__ dn,
    const int* __restrict__ gn,      // [2][4096][10]
    u16* __restrict__ agg)           // bf16 [2][3][4096][128]
{
  __shared__ u16 hbuf[16 * HP];

  int t = blockIdx.y, l = blockIdx.z;
  const int* idx = (t == 0) ? cn : (t == 1) ? dn : gn;
  int rbase = (t == 0) ? 0 : (t == 1) ? 2000 : 6000;
  int nmax  = (t == 0) ? 2000 : (t == 1) ? 4000 : 20000;
  const float* xw = xwb + ((size_t)l * 26000 + rbase) * D;
  const u16* WT = WhT6 + (size_t)(l * 3 + t) * 16384;

  int tid = threadIdx.x, lane = tid & 63, wave = tid >> 6;
  int quad = lane >> 4, l16 = lane & 15;
  int n0 = wave * 32;

  short8 whf[2][4];
#pragma unroll
  for (int nt = 0; nt < 2; ++nt){
    int n = n0 + nt * 16 + l16;
#pragma unroll
    for (int ks = 0; ks < 4; ++ks)
      whf[nt][ks] = *(const short8*)(WT + n * D + ks * 32 + quad * 8);
  }

  for (int i = tid; i < 16 * HP; i += 256) hbuf[i] = 0;   // h0 = zeros

  int brow = blockIdx.x * 16;
  const int* ip = idx + ((size_t)l * NB + brow + quad * 4) * Ssz;
  long arow = ((long)(l * 3 + t) * NB + brow) * D;

  int nidA[4], nidB[4];
  float xwA[8], xwB[8];
#pragma unroll
  for (int r = 0; r < 4; ++r) nidA[r] = min(max(ip[r * Ssz], 0), nmax - 1);
#pragma unroll
  for (int r = 0; r < 4; ++r){
    const float* p = xw + (long)nidA[r] * D + n0 + l16;
    xwA[r] = p[0]; xwA[4 + r] = p[16];
  }
#pragma unroll
  for (int r = 0; r < 4; ++r) nidB[r] = min(max(ip[r * Ssz + 1], 0), nmax - 1);
  __syncthreads();   // hbuf zeros visible

  auto step = [&](int s, float (&xwc)[8], int (&nidn)[4],
                  float (&xwn)[8], int (&nidf)[4]){
    if (s + 1 < Ssz){
#pragma unroll
      for (int r = 0; r < 4; ++r){
        const float* p = xw + (long)nidn[r] * D + n0 + l16;
        xwn[r] = p[0]; xwn[4 + r] = p[16];
      }
    }
    if (s + 2 < Ssz){
#pragma unroll
      for (int r = 0; r < 4; ++r)
        nidf[r] = min(max(ip[r * Ssz + s + 2], 0), nmax - 1);
    }
    short8 hf[4];
#pragma unroll
    for (int ks = 0; ks < 4; ++ks)
      hf[ks] = *(const short8*)(&hbuf[l16 * HP + ks * 32 + quad * 8]);
    f32x4 acc0 = {xwc[0], xwc[1], xwc[2], xwc[3]};
    f32x4 acc1 = {xwc[4], xwc[5], xwc[6], xwc[7]};
#pragma unroll
    for (int ks = 0; ks < 4; ++ks){
      acc0 = __builtin_amdgcn_mfma_f32_16x16x32_bf16(hf[ks], whf[0][ks], acc0, 0, 0, 0);
      acc1 = __builtin_amdgcn_mfma_f32_16x16x32_bf16(hf[ks], whf[1][ks], acc1, 0, 0, 0);
    }
    __syncthreads();   // all waves done READING old h
#pragma unroll
    for (int r = 0; r < 4; ++r){
      float v0 = ftanh(acc0[r]);
      float v1 = ftanh(acc1[r]);
      hbuf[(quad * 4 + r) * HP + n0 + l16]      = f2bf(v0);
      hbuf[(quad * 4 + r) * HP + n0 + 16 + l16] = f2bf(v1);
      if (s == Ssz - 1){
        long o = arow + (long)(quad * 4 + r) * D;
        agg[o + n0 + l16]      = f2bf(v0);
        agg[o + n0 + 16 + l16] = f2bf(v1);
      }
    }
    __syncthreads();   // new h visible
  };

  step(0, xwA, nidB, xwB, nidA);
  step(1, xwB, nidA, xwA, nidB);
  step(2, xwA, nidB, xwB, nidA);
  step(3, xwB, nidA, xwA, nidB);
  step(4, xwA, nidB, xwB, nidA);
  step(5, xwB, nidA, xwA, nidB);
  step(6, xwA, nidB, xwB, nidA);
  step(7, xwB, nidA, xwA, nidB);
  step(8, xwA, nidB, xwB, nidA);
  step(9, xwB, nidA, xwA, nidB);
}

// Fused: h0 gather + both attention layers; h stays in registers between layers.
// one 64-lane wave per row; lane owns elements {2*lane, 2*lane+1}
__global__ __launch_bounds__(256) void att2_kernel(
    const float* __restrict__ drugPf,  // f32 [4000][128]
    const int* __restrict__ center_ids,
    const u16* __restrict__ agg,       // bf16 [2][3][4096][128]
    const float* __restrict__ att_w,   // f32 [2][256]
    float* __restrict__ out)           // f32 [4096][128]
{
  int gt = blockIdx.x * 256 + threadIdx.x;
  int lane = gt & 63;
  int b = gt >> 6;
  int e = 2 * lane;

  int row = min(max(center_ids[b], 0), 3999);
  float h0 = drugPf[(long)row * D + e];
  float h1 = drugPf[(long)row * D + e + 1];

#pragma unroll
  for (int l = 0; l < 2; ++l){
    float c[4][2];
    c[0][0] = h0; c[0][1] = h1;
#pragma unroll
    for (int t = 0; t < 3; ++t){
      long o = ((long)(l * 3 + t) * NB + b) * D + e;
      c[t + 1][0] = bf2f(agg[o]);
      c[t + 1][1] = bf2f(agg[o + 1]);
    }
    const float* aw = att_w + l * 2 * D;
    float as0 = aw[e],     as1 = aw[e + 1];
    float ac0 = aw[D + e], ac1 = aw[D + e + 1];

    float selfp = c[0][0] * as0 + c[0][1] * as1;
    float sc[4];
#pragma unroll
    for (int cc = 0; cc < 4; ++cc) sc[cc] = selfp + c[cc][0] * ac0 + c[cc][1] * ac1;
#pragma unroll
    for (int off = 32; off >= 1; off >>= 1){
#pragma unroll
      for (int cc = 0; cc < 4; ++cc) sc[cc] += __shfl_xor(sc[cc], off, 64);
    }
#pragma unroll
    for (int cc = 0; cc < 4; ++cc) sc[cc] = sc[cc] > 0.f ? sc[cc] : 0.01f * sc[cc];

    float mx = fmaxf(fmaxf(sc[0], sc[1]), fmaxf(sc[2], sc[3]));
    float ex[4], ssum = 0.f;
#pragma unroll
    for (int cc = 0; cc < 4; ++cc){ ex[cc] = expf(sc[cc] - mx); ssum += ex[cc]; }
    float o0 = 0.f, o1 = 0.f;
#pragma unroll
    for (int cc = 0; cc < 4; ++cc){
      float a = ex[cc] / ssum;
      o0 += a * c[cc][0];
      o1 += a * c[cc][1];
    }
    h0 = o0; h1 = o1;
  }
  out[(long)b * D + e]     = h0;
  out[(long)b * D + e + 1] = h1;
}

extern "C" void kernel_launch(void* const* d_in, const int* in_sizes, int n_in,
                              void* d_out, int out_size, void* d_ws, size_t ws_size,
                              hipStream_t stream)
{
  const float* drug_feats = (const float*)d_in[0];   // [4000][1024]
  const float* gene_feats = (const float*)d_in[1];   // [20000][2048]
  const float* cell_tab   = (const float*)d_in[2];   // [2000][128]
  const float* W_drug     = (const float*)d_in[3];   // [1024][128]
  const float* b_drug     = (const float*)d_in[4];   // [128]
  const float* W_gene     = (const float*)d_in[5];   // [2048][128]
  const float* b_gene     = (const float*)d_in[6];   // [128]
  const float* rnn_Wx     = (const float*)d_in[7];   // [2][3][128][128]
  const float* rnn_Wh     = (const float*)d_in[8];
  const float* rnn_b      = (const float*)d_in[9];   // [2][3][128]
  const float* att_w      = (const float*)d_in[10];  // [2][256]
  const int* center_ids   = (const int*)d_in[11];    // [4096]
  const int* cell_neigh   = (const int*)d_in[12];    // [2][4096][10]
  const int* drug_neigh   = (const int*)d_in[13];
  const int* gene_neigh   = (const int*)d_in[14];

  // ws layout (u16 units):
  //  WdT 131072 | WgT 262144 | WxT6 98304 | WhT6 98304 | cellT 256000
  //  | drugPf f32 512000 | xwb f32 6656000 | agg 6*4096*128
  // total bytes = 2*845824 + 4*(512000+6656000) + 2*3145728 = 36,655,104
  u16* ws     = (u16*)d_ws;
  u16* WdT    = ws;
  u16* WgT    = WdT + 131072;
  u16* WxT6   = WgT + 262144;
  u16* WhT6   = WxT6 + 98304;
  u16* cellT  = WhT6 + 98304;
  float* drugPf = (float*)(cellT + 256000);
  float* xwb    = drugPf + 512000;
  u16* agg      = (u16*)(xwb + 6656000);

  float* h = (float*)d_out;               // f32 [4096][128]

  // 1. preamble (one launch)
  prep_kernel<<<2804, 256, 0, stream>>>(W_drug, W_gene, rnn_Wx, rnn_Wh, cell_tab,
                                        WdT, WgT, WxT6, WhT6, cellT);

  // 2+3. dense table projections with fused x@Wx epilogues (mat = l*3 + t)
  proj_gemm<<<63, 256, 0, stream>>>(drug_feats, 1024, 4000, WdT, b_drug,
                                    WxT6 + 1 * 16384, WxT6 + 4 * 16384,
                                    rnn_b + 1 * D,    rnn_b + 4 * D,
                                    xwb + (size_t)(0 * 26000 + 2000) * D,
                                    xwb + (size_t)(1 * 26000 + 2000) * D,
                                    drugPf);
  proj_gemm<<<313, 256, 0, stream>>>(gene_feats, 2048, 20000, WgT, b_gene,
                                     WxT6 + 2 * 16384, WxT6 + 5 * 16384,
                                     rnn_b + 2 * D,    rnn_b + 5 * D,
                                     xwb + (size_t)(0 * 26000 + 6000) * D,
                                     xwb + (size_t)(1 * 26000 + 6000) * D,
                                     (float*)nullptr);

  // 4. cell xw (tiny)
  xw_cell<<<dim3(32, 2), 256, 0, stream>>>(cellT, WxT6, rnn_b, xwb);

  // 5. all 6 (layer,type) RNN aggregations in one launch
  rnn6_kernel<<<dim3(NB / 16, 3, 2), 256, 0, stream>>>(
      xwb, WhT6, cell_neigh, drug_neigh, gene_neigh, agg);

  // 6. h0 gather + both attention layers fused
  att2_kernel<<<NB / 4, 256, 0, stream>>>(drugPf, center_ids, agg, att_w, h);
}